// Round 7
// baseline (519.825 us; speedup 1.0000x reference)
//
#include <hip/hip_runtime.h>
#include <math.h>

#define B_ 16
#define C_ 256
#define N_ 8
#define D_ 32
#define M_ (B_*64*64)              // 65536 rows
#define SCALING 0.17677669529663687f

typedef short  bf16x8 __attribute__((ext_vector_type(8)));
typedef float  f32x4  __attribute__((ext_vector_type(4)));
typedef unsigned short u16x8 __attribute__((ext_vector_type(8)));

__device__ __forceinline__ unsigned short f2bf(float f) {
    unsigned u = __float_as_uint(f);
    u += 0x7fffu + ((u >> 16) & 1u);
    return (unsigned short)(u >> 16);
}
__device__ __forceinline__ float bf2f(unsigned short h) {
    return __uint_as_float(((unsigned)h) << 16);
}
__device__ __forceinline__ void gld16(const void* g, void* l) {
    __builtin_amdgcn_global_load_lds(
        (const __attribute__((address_space(1))) unsigned*)g,
        (__attribute__((address_space(3))) unsigned*)l, 16, 0, 0);
}

// ---------------------------------------------------------------- tables ----
// sint/cost in [pos][d] layout (4096 x 32): epilogue lanes float4-load 4
// consecutive d at fixed pos.
__global__ __launch_bounds__(256) void k_tables(float* __restrict__ sint,
                                                float* __restrict__ cost)
{
    int t = blockIdx.x * 256 + threadIdx.x;   // 131072 = 4096*32
    int p = t >> 5, d = t & 31;
    int j = d >> 1;
    float ang = (float)pow(10000.0, -(double)j / 15.0);
    float arg = (float)p * ang;
    sint[t] = sinf(arg);
    cost[t] = cosf(arg);
}

// ------------------------------------------------------- weight cvt+T -------
// Wt[n][k] = bf16(W[k][n] * scale)  (scale folds SCALING into Wk)
__global__ __launch_bounds__(256) void k_wcvt(
    const float* __restrict__ Wq, const float* __restrict__ Wk,
    const float* __restrict__ Wv, const float* __restrict__ Wo,
    const float* __restrict__ Wfc,
    unsigned short* __restrict__ Wqt, unsigned short* __restrict__ Wkt,
    unsigned short* __restrict__ Wvt, unsigned short* __restrict__ Wot,
    unsigned short* __restrict__ Wfct)
{
    __shared__ float t[32][33];
    int z = blockIdx.z;
    const float* W = z==0?Wq : z==1?Wk : z==2?Wv : z==3?Wo : Wfc;
    unsigned short* Wt = z==0?Wqt : z==1?Wkt : z==2?Wvt : z==3?Wot : Wfct;
    float sc = (z==1) ? SCALING : 1.0f;
    int tx = threadIdx.x & 31, ty = threadIdx.x >> 5;
    int bx = blockIdx.x * 32;   // n base
    int by = blockIdx.y * 32;   // k base
    #pragma unroll
    for (int j = 0; j < 4; ++j)
        t[ty + j*8][tx] = W[(by + ty + j*8) * 256 + bx + tx];  // t[k][n]
    __syncthreads();
    #pragma unroll
    for (int j = 0; j < 4; ++j)
        Wt[(bx + ty + j*8) * 256 + by + tx] = f2bf(t[tx][ty + j*8] * sc);
}

// ------------------------------------------------ prep: x -> xt f32 + x bf16
__global__ __launch_bounds__(256) void k_prep(const float* __restrict__ x,
                                              float* __restrict__ xt,
                                              unsigned short* __restrict__ xbf)
{
    __shared__ float t[32][33];
    int tx = threadIdx.x & 31, ty = threadIdx.x >> 5;
    int bx = blockIdx.x * 32;   // hw base
    int by = blockIdx.y * 32;   // c base
    size_t bo = (size_t)blockIdx.z * (256*4096);
    #pragma unroll
    for (int j = 0; j < 4; ++j)
        t[ty + j*8][tx] = x[bo + (size_t)(by + ty + j*8) * 4096 + bx + tx]; // t[c][hw]
    __syncthreads();
    #pragma unroll
    for (int j = 0; j < 4; ++j) {
        float v = t[tx][ty + j*8];
        size_t o = bo + (size_t)(bx + ty + j*8) * 256 + by + tx;
        xt[o] = v;
        xbf[o] = f2bf(v);
    }
}

// --------------------------------------------------------- MFMA GEMM core ---
// 128x128 tile, BK=64, 4 waves (2x2), each wave 64x64 = 4x4 16x16 frags.
// A (M,256) bf16 row-major; Bt (256,256) bf16 n-major.
// LDS rows are 64 elems (128B); 16B units XOR-swizzled by (row&7) on BOTH
// sides (pre-swizzled global source col for global_load_lds + swizzled read).
// MFMA operands SWAPPED: acc[i][j] lane (c=l&15,g=l>>4) holds
// C[m = i*16+c][n = j*16+g*4 .. +3]  (4 consecutive output channels).
__device__ __forceinline__ void mfma128(
    const unsigned short* A, const unsigned short* Bt, int r0, int c0,
    unsigned short* As, unsigned short* Bs, f32x4 acc[4][4])
{
    const int tid = threadIdx.x;
    const int w = tid >> 6, l = tid & 63;
    const int wr = w >> 1, wc = w & 1;
    const int fr = l & 15, fq = l >> 4;
    const int lrow  = l >> 3;              // 0..7 within 8-row gld16 span
    const int lunit = (l & 7) ^ lrow;      // pre-swizzled global 16B unit
    const int sw = fr & 7;                 // read-side swizzle
    #pragma unroll
    for (int kt = 0; kt < 256; kt += 64) {
        __syncthreads();
        #pragma unroll
        for (int it = 0; it < 4; ++it) {
            int R0 = 32*w + it*8;
            gld16(A  + (size_t)(r0 + R0 + lrow) * 256 + kt + lunit*8, As + R0*64);
            gld16(Bt + (size_t)(c0 + R0 + lrow) * 256 + kt + lunit*8, Bs + R0*64);
        }
        __syncthreads();
        #pragma unroll
        for (int kk = 0; kk < 2; ++kk) {
            const int u = (kk*4 + fq) ^ sw;
            bf16x8 af[4], bfr[4];
            #pragma unroll
            for (int i = 0; i < 4; ++i)
                af[i] = *(const bf16x8*)(As + (wr*64 + i*16 + fr)*64 + u*8);
            #pragma unroll
            for (int j = 0; j < 4; ++j)
                bfr[j] = *(const bf16x8*)(Bs + (wc*64 + j*16 + fr)*64 + u*8);
            #pragma unroll
            for (int i = 0; i < 4; ++i)
                #pragma unroll
                for (int j = 0; j < 4; ++j)
                    acc[i][j] = __builtin_amdgcn_mfma_f32_16x16x32_bf16(
                        bfr[j], af[i], acc[i][j], 0, 0, 0);
        }
    }
}

// ------------------------------------------------------------- QKV GEMM -----
// z: 0=q,1=k,2=v. Epilogue: bias (k scaled), in-register RoPE pairs, ushort4
// stores to (b,n,pos,d).
__global__ __launch_bounds__(256) void k_qkv(
    const unsigned short* __restrict__ xbf,
    const unsigned short* __restrict__ Wqt, const unsigned short* __restrict__ Wkt,
    const unsigned short* __restrict__ Wvt,
    const float* __restrict__ bq, const float* __restrict__ bk,
    const float* __restrict__ bv,
    unsigned short* __restrict__ qb, unsigned short* __restrict__ kb,
    unsigned short* __restrict__ vb,
    const float* __restrict__ sint, const float* __restrict__ cost)
{
    __shared__ __align__(16) unsigned short As[8192], Bs[8192];
    int z = blockIdx.z;
    const unsigned short* Bt = z==0?Wqt : z==1?Wkt : Wvt;
    const float* bias = z==0?bq : z==1?bk : bv;
    unsigned short* dst = z==0?qb : z==1?kb : vb;
    int r0 = blockIdx.x * 128, c0 = blockIdx.y * 128;

    f32x4 acc[4][4];
    #pragma unroll
    for (int i = 0; i < 4; ++i)
        #pragma unroll
        for (int j = 0; j < 4; ++j) { f32x4 zr = {0.f,0.f,0.f,0.f}; acc[i][j] = zr; }
    mfma128(xbf, Bt, r0, c0, As, Bs, acc);

    int l = threadIdx.x & 63, w = threadIdx.x >> 6;
    int wr = w>>1, wc = w&1, c = l&15, g = l>>4;
    float sc = (z==1) ? SCALING : 1.0f;
    #pragma unroll
    for (int i = 0; i < 4; ++i) {
        int rbase = r0 + wr*64 + i*16 + c;
        int b = rbase >> 12, pos = rbase & 4095;
        #pragma unroll
        for (int j = 0; j < 4; ++j) {
            int nb = c0 + wc*64 + j*16 + g*4;
            int nh = nb >> 5, dl = nb & 31;
            float4 b4 = *(const float4*)(bias + nb);
            f32x4 v = acc[i][j];
            v[0] += b4.x*sc; v[1] += b4.y*sc; v[2] += b4.z*sc; v[3] += b4.w*sc;
            if (z < 2) {
                float4 s4 = *(const float4*)(sint + (size_t)pos*32 + dl);
                float4 c4 = *(const float4*)(cost + (size_t)pos*32 + dl);
                float e0 = v[0]*c4.x - v[1]*s4.x;
                float o0 = v[1]*c4.y + v[0]*s4.y;
                float e1 = v[2]*c4.z - v[3]*s4.z;
                float o1 = v[3]*c4.w + v[2]*s4.w;
                v[0]=e0; v[1]=o0; v[2]=e1; v[3]=o1;
            }
            ushort4 ov = make_ushort4(f2bf(v[0]), f2bf(v[1]), f2bf(v[2]), f2bf(v[3]));
            *(ushort4*)(dst + (size_t)(b*8 + nh)*131072 + (size_t)pos*32 + dl) = ov;
        }
    }
}

// ---------------------------------------------------------- plain bf16 GEMM -
// out fp32 (M,256) = A(M,256)bf16 @ Bt^T + bias ; float4 stores.
__global__ __launch_bounds__(256) void k_gemm_bf(
    const unsigned short* __restrict__ A, const unsigned short* __restrict__ Bt,
    const float* __restrict__ bias, float* __restrict__ out)
{
    __shared__ __align__(16) unsigned short As[8192], Bs[8192];
    int r0 = blockIdx.x * 128, c0 = blockIdx.y * 128;
    f32x4 acc[4][4];
    #pragma unroll
    for (int i = 0; i < 4; ++i)
        #pragma unroll
        for (int j = 0; j < 4; ++j) { f32x4 zr = {0.f,0.f,0.f,0.f}; acc[i][j] = zr; }
    mfma128(A, Bt, r0, c0, As, Bs, acc);
    int l = threadIdx.x & 63, w = threadIdx.x >> 6;
    int wr = w>>1, wc = w&1, c = l&15, g = l>>4;
    #pragma unroll
    for (int i = 0; i < 4; ++i) {
        int m = r0 + wr*64 + i*16 + c;
        #pragma unroll
        for (int j = 0; j < 4; ++j) {
            int nb = c0 + wc*64 + j*16 + g*4;
            float4 b4 = *(const float4*)(bias + nb);
            f32x4 v = acc[i][j];
            float4 o4 = make_float4(v[0]+b4.x, v[1]+b4.y, v[2]+b4.z, v[3]+b4.w);
            *(float4*)(out + (size_t)m*256 + nb) = o4;
        }
    }
}

// -------------------------------------------------------------- LePE conv ---
// depthwise 5x5, pad 2. v bf16 (b,n,pos,d); out fp32 (b,h,w,c), c=n*32+d.
__global__ __launch_bounds__(256) void k_conv(
    const unsigned short* __restrict__ v, const float* __restrict__ cw,
    const float* __restrict__ cb, float* __restrict__ out)
{
    __shared__ float vs[5*68*36];
    __shared__ float wts[25*32];
    int h = blockIdx.x, n = blockIdx.y, b = blockIdx.z;
    int tid = threadIdx.x;
    for (int i = tid; i < 5*68*36; i += 256) vs[i] = 0.f;
    for (int i = tid; i < 800; i += 256) {
        int tap = i >> 5, d = i & 31;
        wts[i] = cw[tap*256 + n*32 + d];
    }
    __syncthreads();
    const unsigned short* vb_ = v + (size_t)((b*8 + n)*64) * 2048;
    #pragma unroll
    for (int it = 0; it < 5; ++it) {
        int f  = tid + it*256;        // 0..1279 : 5 rows x 256 u16x8 chunks
        int rr = f >> 8;
        int f2 = f & 255;
        int w  = f2 >> 2, d8 = (f2 & 3) * 8;
        int hh = h + rr - 2;
        if (hh >= 0 && hh < 64) {
            u16x8 vv = *(const u16x8*)(vb_ + hh*2048 + w*32 + d8);
            float* dp = vs + (rr*68 + w + 2)*36 + d8;
            #pragma unroll
            for (int e = 0; e < 8; ++e) dp[e] = bf2f(vv[e]);
        }
    }
    __syncthreads();
    int d = tid & 31, wq = tid >> 5;
    float wreg[25];
    #pragma unroll
    for (int t5 = 0; t5 < 25; ++t5) wreg[t5] = wts[t5*32 + d];
    float bias = cb[n*32 + d];
    for (int w = wq; w < 64; w += 8) {
        float acc = bias;
        #pragma unroll
        for (int dy = 0; dy < 5; ++dy)
            #pragma unroll
            for (int dx = 0; dx < 5; ++dx)
                acc = fmaf(vs[(dy*68 + w + dx)*36 + d], wreg[dy*5+dx], acc);
        out[(size_t)((b*64 + h)*64 + w)*256 + n*32 + d] = acc;
    }
}

// -------------------------------------------------------- MFMA attention ----
// One wave per (b,n,seq-group). QK^T and PV on matrix cores; mask analytic;
// softmax via shfl over 16-lane groups; P and V^T staged in wave-private LDS
// (no barriers). dir0: in-place v5 over own V region. dir1: +lepe -> bf16 A_y.
__global__ __launch_bounds__(256, 3) void k_attn_mfma(
    const unsigned short* __restrict__ Qb, const unsigned short* __restrict__ Kb,
    const unsigned short* Vb, const float* __restrict__ lepe,
    unsigned short* Ob, int dir)
{
    __shared__ unsigned short S[4 * 4864];   // per wave: Vt[32][72] + Ps[64][40]
    int tid = threadIdx.x;
    int wv = tid >> 6, l = tid & 63;
    int gid = blockIdx.x * 4 + wv;
    int n = (gid >> 6) & 7;
    int c = l & 15, g = l >> 4;
    size_t base; int sstr;
    if (dir == 0) { base = (size_t)gid * 2048;                               sstr = 32;   }
    else          { base = (size_t)(gid >> 6) * 131072 + (size_t)(gid & 63) * 32; sstr = 2048; }

    unsigned short* Vt = S + wv * 4864;     // [32][72] : V^T (d, k)
    unsigned short* Ps = Vt + 2304;         // [64][40] : P half (k-block of 32)

    float decayf = (float)log(1.0 - exp2(-1.0 - 3.0 * (double)n / 8.0));

    // ---- stage V^T (lane l owns pos l) ----
    #pragma unroll
    for (int it = 0; it < 4; ++it) {
        u16x8 vv = *(const u16x8*)(Vb + base + (size_t)l * sstr + it*8);
        #pragma unroll
        for (int e = 0; e < 8; ++e)
            Vt[(it*8 + e)*72 + l] = vv[e];
    }

    // ---- Q/K fragments straight from global (A/B frag: row=c, k=g*8..) ----
    bf16x8 qf[4], kf[4];
    #pragma unroll
    for (int i = 0; i < 4; ++i) {
        qf[i] = *(const bf16x8*)(Qb + base + (size_t)(i*16 + c) * sstr + g*8);
        kf[i] = *(const bf16x8*)(Kb + base + (size_t)(i*16 + c) * sstr + g*8);
    }

    // ---- QK^T : 16 MFMA ----
    f32x4 acc[4][4];
    #pragma unroll
    for (int i = 0; i < 4; ++i)
        #pragma unroll
        for (int j = 0; j < 4; ++j) { f32x4 zr = {0.f,0.f,0.f,0.f}; acc[i][j] = zr; }
    #pragma unroll
    for (int i = 0; i < 4; ++i)
        #pragma unroll
        for (int j = 0; j < 4; ++j)
            acc[i][j] = __builtin_amdgcn_mfma_f32_16x16x32_bf16(
                qf[i], kf[j], acc[i][j], 0, 0, 0);

    // ---- mask + softmax (row q = i*16 + g*4 + r; col k = j*16 + c) ----
    float rinv[4][4];
    #pragma unroll
    for (int i = 0; i < 4; ++i) {
        #pragma unroll
        for (int r = 0; r < 4; ++r) {
            float qi = (float)(i*16 + g*4 + r);
            float m = -1e30f;
            #pragma unroll
            for (int j = 0; j < 4; ++j) {
                float ki = (float)(j*16 + c);
                acc[i][j][r] += fabsf(qi - ki) * decayf;
                m = fmaxf(m, acc[i][j][r]);
            }
            m = fmaxf(m, __shfl_xor(m, 1, 16));
            m = fmaxf(m, __shfl_xor(m, 2, 16));
            m = fmaxf(m, __shfl_xor(m, 4, 16));
            m = fmaxf(m, __shfl_xor(m, 8, 16));
            float s = 0.f;
            #pragma unroll
            for (int j = 0; j < 4; ++j) {
                float e = __expf(acc[i][j][r] - m);
                acc[i][j][r] = e;
                s += e;
            }
            s += __shfl_xor(s, 1, 16);
            s += __shfl_xor(s, 2, 16);
            s += __shfl_xor(s, 4, 16);
            s += __shfl_xor(s, 8, 16);
            rinv[i][r] = 1.f / s;
        }
    }

    // ---- PV (split over k-halves through LDS): 16 MFMA ----
    f32x4 o[4][2];
    #pragma unroll
    for (int i = 0; i < 4; ++i) { f32x4 zr = {0.f,0.f,0.f,0.f}; o[i][0] = zr; o[i][1] = zr; }
    #pragma unroll
    for (int s = 0; s < 2; ++s) {
        #pragma unroll
        for (int i = 0; i < 4; ++i)
            #pragma unroll
            for (int r = 0; r < 4; ++r)
                #pragma unroll
                for (int jj = 0; jj < 2; ++jj)
                    Ps[(i*16 + g*4 + r)*40 + jj*16 + c] = f2bf(acc[i][2*s + jj][r]);
        bf16x8 vf0 = *(const bf16x8*)(Vt + (     c)*72 + s*32 + g*8);
        bf16x8 vf1 = *(const bf16x8*)(Vt + (16 + c)*72 + s*32 + g*8);
        #pragma unroll
        for (int i = 0; i < 4; ++i) {
            bf16x8 pa = *(const bf16x8*)(Ps + (i*16 + c)*40 + g*8);
            o[i][0] = __builtin_amdgcn_mfma_f32_16x16x32_bf16(pa, vf0, o[i][0], 0, 0, 0);
            o[i][1] = __builtin_amdgcn_mfma_f32_16x16x32_bf16(pa, vf1, o[i][1], 0, 0, 0);
        }
    }

    // ---- epilogue: normalize, write (row q; col d = nn*16 + c) ----
    #pragma unroll
    for (int i = 0; i < 4; ++i) {
        #pragma unroll
        for (int r = 0; r < 4; ++r) {
            int q = i*16 + g*4 + r;
            float ri = rinv[i][r];
            if (dir == 0) {
                Ob[base + (size_t)q*32 + c]      = f2bf(o[i][0][r] * ri);
                Ob[base + (size_t)q*32 + 16 + c] = f2bf(o[i][1][r] * ri);
            } else {
                int b = gid >> 9, w2 = gid & 63;
                size_t idx = ((size_t)((b*64 + q)*64 + w2))*256 + n*32 + c;
                Ob[idx]      = f2bf(o[i][0][r] * ri + lepe[idx]);
                Ob[idx + 16] = f2bf(o[i][1][r] * ri + lepe[idx + 16]);
            }
        }
    }
}

// ---------------------------------------------------------------- LN(a+b) ---
// out may alias A (row-wise in-place). Optionally dual-write bf16.
template<bool BFOUT>
__global__ __launch_bounds__(256) void k_ln(
    const float* A, const float* __restrict__ Bv,
    const float* __restrict__ g, const float* __restrict__ bb,
    float* out, unsigned short* __restrict__ outbf)
{
    int row  = blockIdx.x * 4 + (threadIdx.x >> 6);
    int lane = threadIdx.x & 63;
    size_t off = (size_t)row * 256 + lane*4;
    float4 a4 = *(const float4*)(A + off);
    float4 b4 = *(const float4*)(Bv + off);
    float v0=a4.x+b4.x, v1=a4.y+b4.y, v2=a4.z+b4.z, v3=a4.w+b4.w;
    float s = v0+v1+v2+v3;
    #pragma unroll
    for (int mm = 1; mm < 64; mm <<= 1) s += __shfl_xor(s, mm, 64);
    float mean = s * (1.0f/256.0f);
    float d0=v0-mean, d1=v1-mean, d2=v2-mean, d3=v3-mean;
    float qq = d0*d0 + d1*d1 + d2*d2 + d3*d3;
    #pragma unroll
    for (int mm = 1; mm < 64; mm <<= 1) qq += __shfl_xor(qq, mm, 64);
    float rstd = rsqrtf(qq * (1.0f/256.0f) + 1e-6f);
    float4 g4  = *(const float4*)(g + lane*4);
    float4 be4 = *(const float4*)(bb + lane*4);
    float o0 = g4.x*d0*rstd + be4.x, o1 = g4.y*d1*rstd + be4.y;
    float o2 = g4.z*d2*rstd + be4.z, o3 = g4.w*d3*rstd + be4.w;
    *(float4*)(out + off) = make_float4(o0, o1, o2, o3);
    if (BFOUT) {
        ushort4 ov = make_ushort4(f2bf(o0), f2bf(o1), f2bf(o2), f2bf(o3));
        *(ushort4*)(outbf + off) = ov;
    }
}

// ------------------------------------------------------------- transpose ----
__global__ __launch_bounds__(256) void k_transpose(const float* __restrict__ src,
                                                   float* __restrict__ dst,
                                                   int rows, int cols)
{
    __shared__ float t[32][33];
    int tx = threadIdx.x & 31, ty = threadIdx.x >> 5;
    int bx = blockIdx.x * 32, by = blockIdx.y * 32;
    size_t bo = (size_t)blockIdx.z * rows * cols;
    #pragma unroll
    for (int j = 0; j < 4; ++j)
        t[ty + j*8][tx] = src[bo + (size_t)(by + ty + j*8) * cols + bx + tx];
    __syncthreads();
    #pragma unroll
    for (int j = 0; j < 4; ++j)
        dst[bo + (size_t)(bx + ty + j*8) * rows + by + tx] = t[tx][ty + j*8];
}

// ---------------------------------------------------------------- launch ----
extern "C" void kernel_launch(void* const* d_in, const int* in_sizes, int n_in,
                              void* d_out, int out_size, void* d_ws, size_t ws_size,
                              hipStream_t stream)
{
    (void)in_sizes; (void)n_in; (void)out_size;
    const float* x   = (const float*)d_in[0];
    const float* Wq  = (const float*)d_in[1];
    const float* bq  = (const float*)d_in[2];
    const float* Wk  = (const float*)d_in[3];
    const float* bk  = (const float*)d_in[4];
    const float* Wv  = (const float*)d_in[5];
    const float* bv  = (const float*)d_in[6];
    const float* lw  = (const float*)d_in[7];
    const float* lb  = (const float*)d_in[8];
    const float* Wo  = (const float*)d_in[9];
    const float* bo  = (const float*)d_in[10];
    const float* Wfc = (const float*)d_in[11];
    const float* bfc = (const float*)d_in[12];
    const float* g1  = (const float*)d_in[13];
    const float* b1  = (const float*)d_in[14];
    const float* g2  = (const float*)d_in[15];
    const float* b2  = (const float*)d_in[16];
    float* out = (float*)d_out;

    const size_t NBB = 67108864;   // 64 MB
    const size_t NEED = 3*NBB + 2*524288 + 5*131072;
    if (ws_size < NEED) return;    // clean fail, not a fault

    char* wsb = (char*)d_ws;
    float*          xt   = (float*)wsb;                        // [0,64M) t1 in-place
    unsigned short* xbf  = (unsigned short*)(wsb + NBB);       // [64,96M) xbf/A_y/t1bf
    unsigned short* qb   = (unsigned short*)(wsb + NBB + NBB/2);     // [96,128M)
    unsigned short* kb   = (unsigned short*)(wsb + 2*NBB);           // [128,160M)
    unsigned short* vb   = (unsigned short*)(wsb + 2*NBB + NBB/2);   // [160,192M)
    float*          yb   = (float*)(wsb + NBB + NBB/2);        // y/t2 over qb+kb
    float* sint = (float*)(wsb + 3*NBB);
    float* cost = sint + 131072;
    unsigned short* Wqt  = (unsigned short*)(cost + 131072);
    unsigned short* Wkt  = Wqt + 65536;
    unsigned short* Wvt  = Wkt + 65536;
    unsigned short* Wot  = Wvt + 65536;
    unsigned short* Wfct = Wot + 65536;

    k_tables<<<512, 256, 0, stream>>>(sint, cost);
    k_wcvt<<<dim3(8,8,5), 256, 0, stream>>>(Wq,Wk,Wv,Wo,Wfc,
                                            Wqt,Wkt,Wvt,Wot,Wfct);
    k_prep<<<dim3(128,8,16), 256, 0, stream>>>(x, xt, xbf);
    k_qkv<<<dim3(512,2,3), 256, 0, stream>>>(xbf, Wqt,Wkt,Wvt, bq,bk,bv,
                                             qb,kb,vb, sint,cost);
    k_conv<<<dim3(64,8,16), 256, 0, stream>>>(vb, lw, lb, out);         // lepe -> d_out
    k_attn_mfma<<<2048, 256, 0, stream>>>(qb, kb, vb, nullptr, vb, 0);  // v5 in-place
    k_attn_mfma<<<2048, 256, 0, stream>>>(qb, kb, vb, out, xbf, 1);     // A_y (+lepe)
    k_gemm_bf<<<dim3(512,2), 256, 0, stream>>>(xbf, Wot, bo, yb);       // y
    k_ln<true><<<16384, 256, 0, stream>>>(xt, yb, g1, b1, xt, xbf);     // t1 + t1bf
    k_gemm_bf<<<dim3(512,2), 256, 0, stream>>>(xbf, Wfct, bfc, out);    // f -> d_out
    k_ln<false><<<16384, 256, 0, stream>>>(xt, out, g2, b2, yb, nullptr);// t2
    k_transpose<<<dim3(8,128,16), 256, 0, stream>>>(yb, out, 4096, 256); // final
}

// Round 8
// 496.860 us; speedup vs baseline: 1.0462x; 1.0462x over previous
//
#include <hip/hip_runtime.h>
#include <math.h>

#define B_ 16
#define C_ 256
#define N_ 8
#define D_ 32
#define M_ (B_*64*64)              // 65536 rows
#define SCALING 0.17677669529663687f

typedef short  bf16x8 __attribute__((ext_vector_type(8)));
typedef float  f32x4  __attribute__((ext_vector_type(4)));
typedef unsigned short u16x8 __attribute__((ext_vector_type(8)));

__device__ __forceinline__ unsigned short f2bf(float f) {
    unsigned u = __float_as_uint(f);
    u += 0x7fffu + ((u >> 16) & 1u);
    return (unsigned short)(u >> 16);
}
__device__ __forceinline__ float bf2f(unsigned short h) {
    return __uint_as_float(((unsigned)h) << 16);
}
__device__ __forceinline__ void gld16(const void* g, void* l) {
    __builtin_amdgcn_global_load_lds(
        (const __attribute__((address_space(1))) unsigned*)g,
        (__attribute__((address_space(3))) unsigned*)l, 16, 0, 0);
}

// ---------------------------------------------------------------- tables ----
__global__ __launch_bounds__(256) void k_tables(float* __restrict__ sint,
                                                float* __restrict__ cost)
{
    int t = blockIdx.x * 256 + threadIdx.x;   // 131072 = 4096*32
    int p = t >> 5, d = t & 31;
    int j = d >> 1;
    float ang = (float)pow(10000.0, -(double)j / 15.0);
    float arg = (float)p * ang;
    sint[t] = sinf(arg);
    cost[t] = cosf(arg);
}

// ------------------------------------------------------- weight cvt+T -------
// Wt[n][k] = bf16(W[k][n] * scale)  (scale folds SCALING into Wk)
__global__ __launch_bounds__(256) void k_wcvt(
    const float* __restrict__ Wq, const float* __restrict__ Wk,
    const float* __restrict__ Wv, const float* __restrict__ Wo,
    const float* __restrict__ Wfc,
    unsigned short* __restrict__ Wqt, unsigned short* __restrict__ Wkt,
    unsigned short* __restrict__ Wvt, unsigned short* __restrict__ Wot,
    unsigned short* __restrict__ Wfct)
{
    __shared__ float t[32][33];
    int z = blockIdx.z;
    const float* W = z==0?Wq : z==1?Wk : z==2?Wv : z==3?Wo : Wfc;
    unsigned short* Wt = z==0?Wqt : z==1?Wkt : z==2?Wvt : z==3?Wot : Wfct;
    float sc = (z==1) ? SCALING : 1.0f;
    int tx = threadIdx.x & 31, ty = threadIdx.x >> 5;
    int bx = blockIdx.x * 32;   // n base
    int by = blockIdx.y * 32;   // k base
    #pragma unroll
    for (int j = 0; j < 4; ++j)
        t[ty + j*8][tx] = W[(by + ty + j*8) * 256 + bx + tx];  // t[k][n]
    __syncthreads();
    #pragma unroll
    for (int j = 0; j < 4; ++j)
        Wt[(bx + ty + j*8) * 256 + by + tx] = f2bf(t[tx][ty + j*8] * sc);
}

// ------------------------------------------------ prep: x -> xt f32 + x bf16
__global__ __launch_bounds__(256) void k_prep(const float* __restrict__ x,
                                              float* __restrict__ xt,
                                              unsigned short* __restrict__ xbf)
{
    __shared__ float t[32][33];
    int tx = threadIdx.x & 31, ty = threadIdx.x >> 5;
    int bx = blockIdx.x * 32;   // hw base
    int by = blockIdx.y * 32;   // c base
    size_t bo = (size_t)blockIdx.z * (256*4096);
    #pragma unroll
    for (int j = 0; j < 4; ++j)
        t[ty + j*8][tx] = x[bo + (size_t)(by + ty + j*8) * 4096 + bx + tx]; // t[c][hw]
    __syncthreads();
    #pragma unroll
    for (int j = 0; j < 4; ++j) {
        float v = t[tx][ty + j*8];
        size_t o = bo + (size_t)(bx + ty + j*8) * 256 + by + tx;
        xt[o] = v;
        xbf[o] = f2bf(v);
    }
}

// --------------------------------------------------------- MFMA GEMM core ---
// (4-wave, 128x128 tile, BK=64) for k_qkv. XOR-swizzled both sides.
// acc[i][j] lane (c=l&15,g=l>>4) holds C[m=i*16+c][n=j*16+g*4..+3].
__device__ __forceinline__ void mfma128(
    const unsigned short* A, const unsigned short* Bt, int r0, int c0,
    unsigned short* As, unsigned short* Bs, f32x4 acc[4][4])
{
    const int tid = threadIdx.x;
    const int w = tid >> 6, l = tid & 63;
    const int wr = w >> 1, wc = w & 1;
    const int fr = l & 15, fq = l >> 4;
    const int lrow  = l >> 3;
    const int lunit = (l & 7) ^ lrow;
    const int sw = fr & 7;
    #pragma unroll
    for (int kt = 0; kt < 256; kt += 64) {
        __syncthreads();
        #pragma unroll
        for (int it = 0; it < 4; ++it) {
            int R0 = 32*w + it*8;
            gld16(A  + (size_t)(r0 + R0 + lrow) * 256 + kt + lunit*8, As + R0*64);
            gld16(Bt + (size_t)(c0 + R0 + lrow) * 256 + kt + lunit*8, Bs + R0*64);
        }
        __syncthreads();
        #pragma unroll
        for (int kk = 0; kk < 2; ++kk) {
            const int u = (kk*4 + fq) ^ sw;
            bf16x8 af[4], bfr[4];
            #pragma unroll
            for (int i = 0; i < 4; ++i)
                af[i] = *(const bf16x8*)(As + (wr*64 + i*16 + fr)*64 + u*8);
            #pragma unroll
            for (int j = 0; j < 4; ++j)
                bfr[j] = *(const bf16x8*)(Bs + (wc*64 + j*16 + fr)*64 + u*8);
            #pragma unroll
            for (int i = 0; i < 4; ++i)
                #pragma unroll
                for (int j = 0; j < 4; ++j)
                    acc[i][j] = __builtin_amdgcn_mfma_f32_16x16x32_bf16(
                        bfr[j], af[i], acc[i][j], 0, 0, 0);
        }
    }
}

// ------------------------------------------------------------- QKV GEMM -----
__global__ __launch_bounds__(256) void k_qkv(
    const unsigned short* __restrict__ xbf,
    const unsigned short* __restrict__ Wqt, const unsigned short* __restrict__ Wkt,
    const unsigned short* __restrict__ Wvt,
    const float* __restrict__ bq, const float* __restrict__ bk,
    const float* __restrict__ bv,
    unsigned short* __restrict__ qb, unsigned short* __restrict__ kb,
    unsigned short* __restrict__ vb,
    const float* __restrict__ sint, const float* __restrict__ cost)
{
    __shared__ __align__(16) unsigned short As[8192], Bs[8192];
    int z = blockIdx.z;
    const unsigned short* Bt = z==0?Wqt : z==1?Wkt : Wvt;
    const float* bias = z==0?bq : z==1?bk : bv;
    unsigned short* dst = z==0?qb : z==1?kb : vb;
    int r0 = blockIdx.x * 128, c0 = blockIdx.y * 128;

    f32x4 acc[4][4];
    #pragma unroll
    for (int i = 0; i < 4; ++i)
        #pragma unroll
        for (int j = 0; j < 4; ++j) { f32x4 zr = {0.f,0.f,0.f,0.f}; acc[i][j] = zr; }
    mfma128(xbf, Bt, r0, c0, As, Bs, acc);

    int l = threadIdx.x & 63, w = threadIdx.x >> 6;
    int wr = w>>1, wc = w&1, c = l&15, g = l>>4;
    float sc = (z==1) ? SCALING : 1.0f;
    #pragma unroll
    for (int i = 0; i < 4; ++i) {
        int rbase = r0 + wr*64 + i*16 + c;
        int b = rbase >> 12, pos = rbase & 4095;
        #pragma unroll
        for (int j = 0; j < 4; ++j) {
            int nb = c0 + wc*64 + j*16 + g*4;
            int nh = nb >> 5, dl = nb & 31;
            float4 b4 = *(const float4*)(bias + nb);
            f32x4 v = acc[i][j];
            v[0] += b4.x*sc; v[1] += b4.y*sc; v[2] += b4.z*sc; v[3] += b4.w*sc;
            if (z < 2) {
                float4 s4 = *(const float4*)(sint + (size_t)pos*32 + dl);
                float4 c4 = *(const float4*)(cost + (size_t)pos*32 + dl);
                float e0 = v[0]*c4.x - v[1]*s4.x;
                float o0 = v[1]*c4.y + v[0]*s4.y;
                float e1 = v[2]*c4.z - v[3]*s4.z;
                float o1 = v[3]*c4.w + v[2]*s4.w;
                v[0]=e0; v[1]=o0; v[2]=e1; v[3]=o1;
            }
            ushort4 ov = make_ushort4(f2bf(v[0]), f2bf(v[1]), f2bf(v[2]), f2bf(v[3]));
            *(ushort4*)(dst + (size_t)(b*8 + nh)*131072 + (size_t)pos*32 + dl) = ov;
        }
    }
}

// ------------------------------------- fused GEMM + residual + LN (8 waves) -
// block = 128 rows x 256 cols (FULL width), 512 threads, waves 2x4.
// acc[i][j] lane (c,g): C[m = wr*64+i*16+c][n = wc*64+j*16+g*4..+3].
// TMODE 0: write LN result to outf(f32)+outbf(bf16), row-major.
// TMODE 1: write LN result transposed to outf: outf[(b*256+col)*4096+pos].
template<int TMODE>
__global__ __launch_bounds__(512, 4) void k_gemm_ln(
    const unsigned short* Abf,              // aliased with outbf (own rows only)
    const unsigned short* __restrict__ Bt,
    const float* __restrict__ bias,
    const float* resid,                     // aliased with outf (own rows only)
    const float* __restrict__ gg, const float* __restrict__ be,
    float* outf, unsigned short* outbf)
{
    __shared__ __align__(16) unsigned short As[8192], Bs[16384];
    __shared__ float red_s[4][128], red_q[4][128];
    const int tid = threadIdx.x, w = tid >> 6, l = tid & 63;
    const int wr = w >> 2, wc = w & 3;
    const int fr = l & 15, fq = l >> 4;
    const int lrow = l >> 3, lunit = (l & 7) ^ lrow;
    const int r0 = blockIdx.x * 128;

    f32x4 acc[4][4];
    #pragma unroll
    for (int i = 0; i < 4; ++i)
        #pragma unroll
        for (int j = 0; j < 4; ++j) { f32x4 zr = {0.f,0.f,0.f,0.f}; acc[i][j] = zr; }

    #pragma unroll
    for (int kt = 0; kt < 256; kt += 64) {
        __syncthreads();
        #pragma unroll
        for (int it = 0; it < 2; ++it) {          // A: 128 rows
            int R0 = 8*w + it*64;
            gld16(Abf + (size_t)(r0 + R0 + lrow) * 256 + kt + lunit*8, As + R0*64);
        }
        #pragma unroll
        for (int it = 0; it < 4; ++it) {          // B: 256 cols
            int R0 = 8*w + it*64;
            gld16(Bt + (size_t)(R0 + lrow) * 256 + kt + lunit*8, Bs + R0*64);
        }
        __syncthreads();
        #pragma unroll
        for (int kk = 0; kk < 2; ++kk) {
            const int u = (kk*4 + fq) ^ (fr & 7);
            bf16x8 af[4], bfr[4];
            #pragma unroll
            for (int i = 0; i < 4; ++i)
                af[i] = *(const bf16x8*)(As + (wr*64 + i*16 + fr)*64 + u*8);
            #pragma unroll
            for (int j = 0; j < 4; ++j)
                bfr[j] = *(const bf16x8*)(Bs + (wc*64 + j*16 + fr)*64 + u*8);
            #pragma unroll
            for (int i = 0; i < 4; ++i)
                #pragma unroll
                for (int j = 0; j < 4; ++j)
                    acc[i][j] = __builtin_amdgcn_mfma_f32_16x16x32_bf16(
                        bfr[j], af[i], acc[i][j], 0, 0, 0);
        }
    }

    // ---- bias + residual, per-row partial sums over this wave's 64 cols ----
    const int c = l & 15, g4 = l >> 4;
    float psum[4], pq[4];
    #pragma unroll
    for (int i = 0; i < 4; ++i) {
        int m = r0 + wr*64 + i*16 + c;
        psum[i] = 0.f; pq[i] = 0.f;
        #pragma unroll
        for (int j = 0; j < 4; ++j) {
            int nb = wc*64 + j*16 + g4*4;
            float4 b4 = *(const float4*)(bias + nb);
            float4 x4 = *(const float4*)(resid + (size_t)m*256 + nb);
            f32x4 v = acc[i][j];
            v[0] += b4.x + x4.x; v[1] += b4.y + x4.y;
            v[2] += b4.z + x4.z; v[3] += b4.w + x4.w;
            acc[i][j] = v;
            psum[i] += v[0]+v[1]+v[2]+v[3];
            pq[i]   += v[0]*v[0]+v[1]*v[1]+v[2]*v[2]+v[3]*v[3];
        }
        psum[i] += __shfl_xor(psum[i], 16); psum[i] += __shfl_xor(psum[i], 32);
        pq[i]   += __shfl_xor(pq[i], 16);   pq[i]   += __shfl_xor(pq[i], 32);
    }
    if (l < 16) {
        #pragma unroll
        for (int i = 0; i < 4; ++i) {
            red_s[wc][wr*64 + i*16 + l] = psum[i];
            red_q[wc][wr*64 + i*16 + l] = pq[i];
        }
    }
    __syncthreads();

    // ---- finalize LN per row, write ----
    #pragma unroll
    for (int i = 0; i < 4; ++i) {
        int ml = wr*64 + i*16 + c;
        int m  = r0 + ml;
        float S = red_s[0][ml] + red_s[1][ml] + red_s[2][ml] + red_s[3][ml];
        float Q = red_q[0][ml] + red_q[1][ml] + red_q[2][ml] + red_q[3][ml];
        float mean = S * (1.f/256.f);
        float var  = Q * (1.f/256.f) - mean*mean;
        float rstd = rsqrtf(var + 1e-6f);
        #pragma unroll
        for (int j = 0; j < 4; ++j) {
            int nb = wc*64 + j*16 + g4*4;
            float4 gv = *(const float4*)(gg + nb);
            float4 bv = *(const float4*)(be + nb);
            f32x4 v = acc[i][j];
            float o0 = gv.x*(v[0]-mean)*rstd + bv.x;
            float o1 = gv.y*(v[1]-mean)*rstd + bv.y;
            float o2 = gv.z*(v[2]-mean)*rstd + bv.z;
            float o3 = gv.w*(v[3]-mean)*rstd + bv.w;
            if (TMODE == 0) {
                *(float4*)(outf + (size_t)m*256 + nb) = make_float4(o0,o1,o2,o3);
                *(ushort4*)(outbf + (size_t)m*256 + nb) =
                    make_ushort4(f2bf(o0), f2bf(o1), f2bf(o2), f2bf(o3));
            } else {
                int b = m >> 12, pos = m & 4095;
                size_t obase = ((size_t)b*256 + nb) * 4096 + pos;
                outf[obase]          = o0;
                outf[obase + 4096]   = o1;
                outf[obase + 8192]   = o2;
                outf[obase + 12288]  = o3;
            }
        }
    }
}

// -------------------------------------------------------------- LePE conv ---
__global__ __launch_bounds__(256) void k_conv(
    const unsigned short* __restrict__ v, const float* __restrict__ cw,
    const float* __restrict__ cb, float* __restrict__ out)
{
    __shared__ float vs[5*68*36];
    __shared__ float wts[25*32];
    int h = blockIdx.x, n = blockIdx.y, b = blockIdx.z;
    int tid = threadIdx.x;
    for (int i = tid; i < 5*68*36; i += 256) vs[i] = 0.f;
    for (int i = tid; i < 800; i += 256) {
        int tap = i >> 5, d = i & 31;
        wts[i] = cw[tap*256 + n*32 + d];
    }
    __syncthreads();
    const unsigned short* vb_ = v + (size_t)((b*8 + n)*64) * 2048;
    #pragma unroll
    for (int it = 0; it < 5; ++it) {
        int f  = tid + it*256;
        int rr = f >> 8;
        int f2 = f & 255;
        int w  = f2 >> 2, d8 = (f2 & 3) * 8;
        int hh = h + rr - 2;
        if (hh >= 0 && hh < 64) {
            u16x8 vv = *(const u16x8*)(vb_ + hh*2048 + w*32 + d8);
            float* dp = vs + (rr*68 + w + 2)*36 + d8;
            #pragma unroll
            for (int e = 0; e < 8; ++e) dp[e] = bf2f(vv[e]);
        }
    }
    __syncthreads();
    int d = tid & 31, wq = tid >> 5;
    float wreg[25];
    #pragma unroll
    for (int t5 = 0; t5 < 25; ++t5) wreg[t5] = wts[t5*32 + d];
    float bias = cb[n*32 + d];
    for (int w = wq; w < 64; w += 8) {
        float acc = bias;
        #pragma unroll
        for (int dy = 0; dy < 5; ++dy)
            #pragma unroll
            for (int dx = 0; dx < 5; ++dx)
                acc = fmaf(vs[(dy*68 + w + dx)*36 + d], wreg[dy*5+dx], acc);
        out[(size_t)((b*64 + h)*64 + w)*256 + n*32 + d] = acc;
    }
}

// -------------------------------------------------------- MFMA attention ----
__global__ __launch_bounds__(256, 4) void k_attn_mfma(
    const unsigned short* __restrict__ Qb, const unsigned short* __restrict__ Kb,
    const unsigned short* Vb, const float* __restrict__ lepe,
    unsigned short* Ob, int dir)
{
    __shared__ unsigned short S[4 * 4864];   // per wave: Vt[32][72] + Ps[64][40]
    int tid = threadIdx.x;
    int wv = tid >> 6, l = tid & 63;
    int gid = blockIdx.x * 4 + wv;
    int n = (gid >> 6) & 7;
    int c = l & 15, g = l >> 4;
    size_t base; int sstr;
    if (dir == 0) { base = (size_t)gid * 2048;                               sstr = 32;   }
    else          { base = (size_t)(gid >> 6) * 131072 + (size_t)(gid & 63) * 32; sstr = 2048; }

    unsigned short* Vt = S + wv * 4864;
    unsigned short* Ps = Vt + 2304;

    float decayf = (float)log(1.0 - exp2(-1.0 - 3.0 * (double)n / 8.0));

    #pragma unroll
    for (int it = 0; it < 4; ++it) {
        u16x8 vv = *(const u16x8*)(Vb + base + (size_t)l * sstr + it*8);
        #pragma unroll
        for (int e = 0; e < 8; ++e)
            Vt[(it*8 + e)*72 + l] = vv[e];
    }

    bf16x8 qf[4], kf[4];
    #pragma unroll
    for (int i = 0; i < 4; ++i) {
        qf[i] = *(const bf16x8*)(Qb + base + (size_t)(i*16 + c) * sstr + g*8);
        kf[i] = *(const bf16x8*)(Kb + base + (size_t)(i*16 + c) * sstr + g*8);
    }

    f32x4 acc[4][4];
    #pragma unroll
    for (int i = 0; i < 4; ++i)
        #pragma unroll
        for (int j = 0; j < 4; ++j) { f32x4 zr = {0.f,0.f,0.f,0.f}; acc[i][j] = zr; }
    #pragma unroll
    for (int i = 0; i < 4; ++i)
        #pragma unroll
        for (int j = 0; j < 4; ++j)
            acc[i][j] = __builtin_amdgcn_mfma_f32_16x16x32_bf16(
                qf[i], kf[j], acc[i][j], 0, 0, 0);

    float rinv[4][4];
    #pragma unroll
    for (int i = 0; i < 4; ++i) {
        #pragma unroll
        for (int r = 0; r < 4; ++r) {
            float qi = (float)(i*16 + g*4 + r);
            float m = -1e30f;
            #pragma unroll
            for (int j = 0; j < 4; ++j) {
                float ki = (float)(j*16 + c);
                acc[i][j][r] += fabsf(qi - ki) * decayf;
                m = fmaxf(m, acc[i][j][r]);
            }
            m = fmaxf(m, __shfl_xor(m, 1, 16));
            m = fmaxf(m, __shfl_xor(m, 2, 16));
            m = fmaxf(m, __shfl_xor(m, 4, 16));
            m = fmaxf(m, __shfl_xor(m, 8, 16));
            float s = 0.f;
            #pragma unroll
            for (int j = 0; j < 4; ++j) {
                float e = __expf(acc[i][j][r] - m);
                acc[i][j][r] = e;
                s += e;
            }
            s += __shfl_xor(s, 1, 16);
            s += __shfl_xor(s, 2, 16);
            s += __shfl_xor(s, 4, 16);
            s += __shfl_xor(s, 8, 16);
            rinv[i][r] = 1.f / s;
        }
    }

    f32x4 o[4][2];
    #pragma unroll
    for (int i = 0; i < 4; ++i) { f32x4 zr = {0.f,0.f,0.f,0.f}; o[i][0] = zr; o[i][1] = zr; }
    #pragma unroll
    for (int s = 0; s < 2; ++s) {
        #pragma unroll
        for (int i = 0; i < 4; ++i)
            #pragma unroll
            for (int r = 0; r < 4; ++r)
                #pragma unroll
                for (int jj = 0; jj < 2; ++jj)
                    Ps[(i*16 + g*4 + r)*40 + jj*16 + c] = f2bf(acc[i][2*s + jj][r]);
        bf16x8 vf0 = *(const bf16x8*)(Vt + (     c)*72 + s*32 + g*8);
        bf16x8 vf1 = *(const bf16x8*)(Vt + (16 + c)*72 + s*32 + g*8);
        #pragma unroll
        for (int i = 0; i < 4; ++i) {
            bf16x8 pa = *(const bf16x8*)(Ps + (i*16 + c)*40 + g*8);
            o[i][0] = __builtin_amdgcn_mfma_f32_16x16x32_bf16(pa, vf0, o[i][0], 0, 0, 0);
            o[i][1] = __builtin_amdgcn_mfma_f32_16x16x32_bf16(pa, vf1, o[i][1], 0, 0, 0);
        }
    }

    #pragma unroll
    for (int i = 0; i < 4; ++i) {
        #pragma unroll
        for (int r = 0; r < 4; ++r) {
            int q = i*16 + g*4 + r;
            float ri = rinv[i][r];
            if (dir == 0) {
                Ob[base + (size_t)q*32 + c]      = f2bf(o[i][0][r] * ri);
                Ob[base + (size_t)q*32 + 16 + c] = f2bf(o[i][1][r] * ri);
            } else {
                int b = gid >> 9, w2 = gid & 63;
                size_t idx = ((size_t)((b*64 + q)*64 + w2))*256 + n*32 + c;
                Ob[idx]      = f2bf(o[i][0][r] * ri + lepe[idx]);
                Ob[idx + 16] = f2bf(o[i][1][r] * ri + lepe[idx + 16]);
            }
        }
    }
}

// ---------------------------------------------------------------- launch ----
extern "C" void kernel_launch(void* const* d_in, const int* in_sizes, int n_in,
                              void* d_out, int out_size, void* d_ws, size_t ws_size,
                              hipStream_t stream)
{
    (void)in_sizes; (void)n_in; (void)out_size;
    const float* x   = (const float*)d_in[0];
    const float* Wq  = (const float*)d_in[1];
    const float* bq  = (const float*)d_in[2];
    const float* Wk  = (const float*)d_in[3];
    const float* bk  = (const float*)d_in[4];
    const float* Wv  = (const float*)d_in[5];
    const float* bv  = (const float*)d_in[6];
    const float* lw  = (const float*)d_in[7];
    const float* lb  = (const float*)d_in[8];
    const float* Wo  = (const float*)d_in[9];
    const float* bo  = (const float*)d_in[10];
    const float* Wfc = (const float*)d_in[11];
    const float* bfc = (const float*)d_in[12];
    const float* g1  = (const float*)d_in[13];
    const float* b1  = (const float*)d_in[14];
    const float* g2  = (const float*)d_in[15];
    const float* b2  = (const float*)d_in[16];
    float* out = (float*)d_out;

    const size_t NBB = 67108864;   // 64 MB
    const size_t NEED = 3*NBB + 2*524288 + 5*131072;
    if (ws_size < NEED) return;    // clean fail, not a fault

    char* wsb = (char*)d_ws;
    float*          xt   = (float*)wsb;                        // [0,64M): xt -> t1 (in-place)
    unsigned short* xbf  = (unsigned short*)(wsb + NBB);       // [64,96M): xbf -> A_y -> t1bf
    unsigned short* qb   = (unsigned short*)(wsb + NBB + NBB/2);     // [96,128M)
    unsigned short* kb   = (unsigned short*)(wsb + 2*NBB);           // [128,160M)
    unsigned short* vb   = (unsigned short*)(wsb + 2*NBB + NBB/2);   // [160,192M)
    float* sint = (float*)(wsb + 3*NBB);
    float* cost = sint + 131072;
    unsigned short* Wqt  = (unsigned short*)(cost + 131072);
    unsigned short* Wkt  = Wqt + 65536;
    unsigned short* Wvt  = Wkt + 65536;
    unsigned short* Wot  = Wvt + 65536;
    unsigned short* Wfct = Wot + 65536;

    k_tables<<<512, 256, 0, stream>>>(sint, cost);
    k_wcvt<<<dim3(8,8,5), 256, 0, stream>>>(Wq,Wk,Wv,Wo,Wfc,
                                            Wqt,Wkt,Wvt,Wot,Wfct);
    k_prep<<<dim3(128,8,16), 256, 0, stream>>>(x, xt, xbf);
    k_qkv<<<dim3(512,2,3), 256, 0, stream>>>(xbf, Wqt,Wkt,Wvt, bq,bk,bv,
                                             qb,kb,vb, sint,cost);
    k_conv<<<dim3(64,8,16), 256, 0, stream>>>(vb, lw, lb, out);         // lepe -> d_out
    k_attn_mfma<<<2048, 256, 0, stream>>>(qb, kb, vb, nullptr, vb, 0);  // v5 in-place
    k_attn_mfma<<<2048, 256, 0, stream>>>(qb, kb, vb, out, xbf, 1);     // A_y (+lepe) -> xbf
    // y = A_y@Wo + bo; t1 = LN(xt + y) -> xt (f32) + xbf (bf16)
    k_gemm_ln<0><<<512, 512, 0, stream>>>(xbf, Wot, bo, xt, g1, b1, xt, xbf);
    // f = t1bf@Wfc + bfc; t2 = LN(t1 + f) -> out transposed (b,c,h,w)
    k_gemm_ln<1><<<512, 512, 0, stream>>>(xbf, Wfct, bfc, xt, g2, b2, out, nullptr);
}